// Round 5
// baseline (383.115 us; speedup 1.0000x reference)
//
#include <hip/hip_runtime.h>
#include <stdint.h>

// ---------------------------------------------------------------------------
// LatentMoE forward, MI355X (gfx950). ONE persistent kernel (normal launch),
// 256 blocks x 256 threads, software grid barrier between phases:
//  P0 pack -> P1 gemm1(+shared SwiGLU) -> P2 router -> P3 GU gemm(+SwiGLU)
//  -> P4 down gemm -> P5 combine(+z reduce) -> P6 final gemm
// Barrier slots live in d_ws and are zeroed via hipMemsetAsync each call.
// ---------------------------------------------------------------------------

using f32x4 = __attribute__((ext_vector_type(4))) float;
using s16x8 = __attribute__((ext_vector_type(8))) short;

#define MFMA_BF16(a, b, c) __builtin_amdgcn_mfma_f32_16x16x32_bf16((a), (b), (c), 0, 0, 0)

__device__ __forceinline__ unsigned short f2bf(float f) {
  union { float f; uint32_t u; } v; v.f = f;
  uint32_t u = v.u;
  u += 0x7FFFu + ((u >> 16) & 1u);
  return (unsigned short)(u >> 16);
}
__device__ __forceinline__ float bf2f(unsigned short h) {
  union { uint32_t u; float f; } v; v.u = ((uint32_t)h) << 16;
  return v.f;
}
__device__ __forceinline__ float silu_f(float x) { return x / (1.f + expf(-x)); }

__device__ __forceinline__ void cvt16(const float* __restrict__ src,
                                      unsigned short* __restrict__ dst) {
  if (src) {
#pragma unroll
    for (int i = 0; i < 4; ++i) {
      float4 v = *(const float4*)(src + i * 4);
      *(ushort4*)(dst + i * 4) =
          make_ushort4(f2bf(v.x), f2bf(v.y), f2bf(v.z), f2bf(v.w));
    }
  } else {
#pragma unroll
    for (int i = 0; i < 4; ++i) *(ushort4*)(dst + i * 4) = make_ushort4(0, 0, 0, 0);
  }
}

union SMem {
  float tp[32][33];
  struct { unsigned short As[3 * 4096]; unsigned short Bs[3 * 4096]; } g;
};

struct MegaArgs {
  const float *x, *gate, *down, *sgu, *sdw, *up, *egu, *edw, *bias;
  unsigned short *xb, *Wcat, *Bf, *egut, *edwt, *Abuf, *lat_g, *hide, *ybuf;
  float *C1, *lse2, *out;
  int *counts, *slot_nk;
  float *gw_nk;
  int *bars;  // software grid-barrier slots (zeroed before launch)
};

// ---------------------------------------------------------------------------
// Software grid barrier. All 256 blocks are co-resident (1 block/CU floor on
// 256 CUs), so spin-wait is safe. Release/acquire via __threadfence (drains
// vmcnt, L2 writeback/invalidate for cross-XCD visibility).
// ---------------------------------------------------------------------------
__device__ __forceinline__ void grid_barrier(int* bar, int nblk) {
  __syncthreads();
  if (threadIdx.x == 0) {
    __threadfence();  // release: prior writes visible device-wide
    __hip_atomic_fetch_add(bar, 1, __ATOMIC_RELEASE, __HIP_MEMORY_SCOPE_AGENT);
    while (__hip_atomic_load(bar, __ATOMIC_ACQUIRE, __HIP_MEMORY_SCOPE_AGENT) < nblk)
      __builtin_amdgcn_s_sleep(2);
    __threadfence();  // acquire: don't read stale L1/L2
  }
  __syncthreads();
}

// ---------------------------------------------------------------------------
// P0: pack unit (4096 elems each). Units:
//  [0,608) Wcat | [608,928) Bf | [928,1184) xb | [1184,9376) egut T |
//  [9376,13472) edwt T
// ---------------------------------------------------------------------------
__device__ void pack_unit(int b, int t, const MegaArgs& a, SMem& sm) {
  if (b < 608) {
    const int r = b * 4 + (t >> 6), c = (t & 63) * 16;
    const float* src;
    if (r < 64)       src = a.gate + (size_t)r * 1024 + c;
    else if (r < 320) src = a.down + (size_t)(r - 64) * 1024 + c;
    else if (r < 384) src = nullptr;
    else {
      const int i = r - 384;
      src = a.sgu + (size_t)((i >> 1) + (i & 1) * 1024) * 1024 + c;
    }
    cvt16(src, a.Wcat + (size_t)r * 1024 + c);
  } else if (b < 928) {
    const int idx = (b - 608) * 4096 + t * 16;
    const int row = idx / 1280, col = idx - row * 1280;
    const float* src = (col < 1024) ? a.sdw + (size_t)row * 1024 + col
                                    : a.up + (size_t)row * 256 + (col - 1024);
    cvt16(src, a.Bf + idx);
  } else if (b < 1184) {
    const int idx = (b - 928) * 4096 + t * 16;
    cvt16(a.x + idx, a.xb + idx);
  } else {
    const float* src; unsigned short* dst; int lds, tr, tc; bool inter;
    if (b < 9376) {
      const int q = b - 1184, e = q >> 7, tt = q & 127;
      tr = tt >> 4; tc = tt & 15; lds = 512; inter = true;
      src = a.egu + (size_t)e * 131072; dst = a.egut + (size_t)e * 131072;
    } else {
      const int q = b - 9376, e = q >> 6, tt = q & 63;
      tr = tt >> 3; tc = tt & 7; lds = 256; inter = false;
      src = a.edw + (size_t)e * 65536; dst = a.edwt + (size_t)e * 65536;
    }
    const int r = t >> 3, c4 = (t & 7) * 4;
    float4 v = *(const float4*)(src + (size_t)(tr * 32 + r) * lds + tc * 32 + c4);
    sm.tp[r][c4 + 0] = v.x; sm.tp[r][c4 + 1] = v.y;
    sm.tp[r][c4 + 2] = v.z; sm.tp[r][c4 + 3] = v.w;
    __syncthreads();
    const int n = tc * 32 + r;
    const int orow = inter ? ((n < 256) ? 2 * n : 2 * (n - 256) + 1) : n;
    ushort4 o = make_ushort4(f2bf(sm.tp[c4 + 0][r]), f2bf(sm.tp[c4 + 1][r]),
                             f2bf(sm.tp[c4 + 2][r]), f2bf(sm.tp[c4 + 3][r]));
    *(ushort4*)(dst + (size_t)orow * 256 + tr * 32 + c4) = o;
    __syncthreads();  // next unit re-writes sm.tp
  }
}

// ---------------------------------------------------------------------------
// GEMM core (R3 pipeline: triple-buffered LDS, counted vmcnt, raw s_barrier)
// ---------------------------------------------------------------------------
struct EpiArgs { int mode; void* out; int ldo; int coff; };

__device__ __forceinline__ void stage_tile(const unsigned short* __restrict__ G, int ldg,
                                           int row0, int kt, unsigned short* lbuf,
                                           int wid, int lane) {
#pragma unroll
  for (int j = 0; j < 2; ++j) {
    const int o = j * 4096 + wid * 1024 + lane * 16;
    const int kh = o >> 11;
    const int row = (o & 2047) >> 4;
    const unsigned short* src = G + (size_t)(row0 + row) * ldg + kt * 32 + kh * 8;
    __builtin_amdgcn_global_load_lds(
        (const __attribute__((address_space(1))) void*)src,
        (__attribute__((address_space(3))) void*)(lbuf + (size_t)(j * 2048 + wid * 512)),
        16, 0, 0);
  }
}

__device__ __forceinline__ void wave_fence() { asm volatile("" ::: "memory"); }

__device__ void gemm_tile(const unsigned short* __restrict__ A, int lda,
                          const unsigned short* __restrict__ B, int ldb,
                          int K, int m0, int n0, EpiArgs epi,
                          unsigned short* As, unsigned short* Bs) {
  __syncthreads();  // LDS may be in use by a previous tile/phase of this block
  const int tid = threadIdx.x;
  const int wid = tid >> 6, lane = tid & 63;
  const int wm = wid >> 1, wn = wid & 1;

  f32x4 acc[4][4] = {};
  const int NT = K >> 5;

  stage_tile(A, lda, m0, 0, As, wid, lane);
  stage_tile(B, ldb, n0, 0, Bs, wid, lane);
  if (NT > 1) {
    stage_tile(A, lda, m0, 1, As + 4096, wid, lane);
    stage_tile(B, ldb, n0, 1, Bs + 4096, wid, lane);
  }

  const int kh = lane >> 4, r16 = lane & 15;
  int cur = 0;
  for (int kt = 0; kt < NT; ++kt) {
    if (kt + 1 < NT) asm volatile("s_waitcnt vmcnt(4)" ::: "memory");
    else             asm volatile("s_waitcnt vmcnt(0)" ::: "memory");
    wave_fence();
    __builtin_amdgcn_s_barrier();
    wave_fence();

    const unsigned short* Ab = As + cur * 4096;
    const unsigned short* Bb = Bs + cur * 4096;
    s16x8 af[4], bfr[4];
#pragma unroll
    for (int m = 0; m < 4; ++m)
      af[m] = *(const s16x8*)(Ab + kh * 1024 + (wm * 64 + m * 16 + r16) * 8);
#pragma unroll
    for (int n = 0; n < 4; ++n)
      bfr[n] = *(const s16x8*)(Bb + kh * 1024 + (wn * 64 + n * 16 + r16) * 8);

    if (kt + 2 < NT) {
      const int nb = (cur + 2 >= 3) ? cur - 1 : cur + 2;
      stage_tile(A, lda, m0, kt + 2, As + nb * 4096, wid, lane);
      stage_tile(B, ldb, n0, kt + 2, Bs + nb * 4096, wid, lane);
    }

    __builtin_amdgcn_s_setprio(1);
#pragma unroll
    for (int m = 0; m < 4; ++m)
#pragma unroll
      for (int n = 0; n < 4; ++n)
        acc[m][n] = MFMA_BF16(af[m], bfr[n], acc[m][n]);
    __builtin_amdgcn_s_setprio(0);

    cur = (cur + 1 == 3) ? 0 : cur + 1;
  }

#pragma unroll
  for (int m = 0; m < 4; ++m) {
    const int rb = m0 + wm * 64 + m * 16 + (lane >> 4) * 4;
#pragma unroll
    for (int n = 0; n < 4; ++n) {
      const int c = n0 + wn * 64 + n * 16 + (lane & 15);
      if (epi.mode == 0) {
        float* O = (float*)epi.out;
#pragma unroll
        for (int j = 0; j < 4; ++j) O[(size_t)(rb + j) * epi.ldo + c] = acc[m][n][j];
      } else if (epi.mode == 1) {
        unsigned short* O = (unsigned short*)epi.out;
#pragma unroll
        for (int j = 0; j < 4; ++j)
          O[(size_t)(rb + j) * epi.ldo + c] = f2bf(acc[m][n][j]);
      } else {
        unsigned short* O = (unsigned short*)epi.out;
        const int col = (c - epi.coff) >> 1;
#pragma unroll
        for (int j = 0; j < 4; ++j) {
          const float v = acc[m][n][j];
          const float u = __shfl_xor(v, 1);
          if (!(lane & 1))
            O[(size_t)(rb + j) * epi.ldo + col] = f2bf(silu_f(v) * u);
        }
      }
    }
  }
}

// ---------------------------------------------------------------------------
// P2: router (one wave per token; 4 tokens per block)
// ---------------------------------------------------------------------------
__device__ void router_block(int b, int tid, const MegaArgs& a) {
  const int n = b * 4 + (tid >> 6);
  const int lane = tid & 63;
  const float* row = a.C1 + (size_t)n * 384;
  const float logit = row[lane];

  float mx = logit;
#pragma unroll
  for (int d = 32; d; d >>= 1) mx = fmaxf(mx, __shfl_xor(mx, d));
  float se = expf(logit - mx);
#pragma unroll
  for (int d = 32; d; d >>= 1) se += __shfl_xor(se, d);
  if (lane == 0) {
    const float lse = mx + logf(se);
    a.lse2[n] = lse * lse;
  }

  const float aff = 1.f / (1.f + expf(-logit));
  float s = aff + a.bias[lane];

  float asum = 0.f;
  int e_mine = 0; float a_mine = 0.f;
#pragma unroll
  for (int k = 0; k < 8; ++k) {
    float m2 = s;
#pragma unroll
    for (int d = 32; d; d >>= 1) m2 = fmaxf(m2, __shfl_xor(m2, d));
    const unsigned long long blt = __ballot(s == m2);
    const int idx = __ffsll(blt) - 1;
    const float af_ = __shfl(aff, idx);
    asum += af_;
    if (lane == k) { e_mine = idx; a_mine = af_; }
    if (lane == idx) s = -3.0e38f;
  }
  const float inv = 1.f / (asum + 1e-9f);

  int slot = 0;
  if (lane < 8) {
    int pos = atomicAdd(&a.counts[e_mine], 1);
    if (pos > 255) pos = 255;
    slot = e_mine * 256 + pos;
    a.slot_nk[(size_t)n * 8 + lane] = slot;
    a.gw_nk[(size_t)n * 8 + lane] = a_mine * inv;
  }

  const float4 lv = *(const float4*)(row + 64 + lane * 4);
  const ushort4 lb = make_ushort4(f2bf(lv.x), f2bf(lv.y), f2bf(lv.z), f2bf(lv.w));
#pragma unroll
  for (int k = 0; k < 8; ++k) {
    const int sl = __shfl(slot, k);
    *(ushort4*)(a.lat_g + (size_t)sl * 256 + lane * 4) = lb;
  }
}

// ---------------------------------------------------------------------------
// P5: combine (4 tokens per block) + z-loss reduce on block 0
// ---------------------------------------------------------------------------
__device__ void combine_block(int b, int tid, const MegaArgs& a, SMem& sm) {
  const int n = b * 4 + (tid >> 6);
  const int l4 = (tid & 63) * 4;
  float a0 = 0.f, a1 = 0.f, a2 = 0.f, a3 = 0.f;
#pragma unroll
  for (int k = 0; k < 8; ++k) {
    const int sl = a.slot_nk[(size_t)n * 8 + k];
    const float g = a.gw_nk[(size_t)n * 8 + k];
    const ushort4 yv = *(const ushort4*)(a.ybuf + (size_t)sl * 256 + l4);
    a0 += g * bf2f(yv.x); a1 += g * bf2f(yv.y);
    a2 += g * bf2f(yv.z); a3 += g * bf2f(yv.w);
  }
  *(ushort4*)(a.Abuf + (size_t)n * 1280 + 1024 + l4) =
      make_ushort4(f2bf(a0), f2bf(a1), f2bf(a2), f2bf(a3));

  if (b == 0) {
    __syncthreads();
    float s = a.lse2[tid] + a.lse2[tid + 256] + a.lse2[tid + 512] + a.lse2[tid + 768];
    ((float*)sm.tp)[tid] = s;
    __syncthreads();
    for (int d = 128; d; d >>= 1) {
      if (tid < d) ((float*)sm.tp)[tid] += ((float*)sm.tp)[tid + d];
      __syncthreads();
    }
    if (tid == 0) a.out[1048576] = 0.001f * ((float*)sm.tp)[0] * (1.f / 1024.f);
  }
}

// ---------------------------------------------------------------------------
__global__ __launch_bounds__(256, 1) void moe_mega(MegaArgs a) {
  __shared__ SMem sm;
  const int b = blockIdx.x, tid = threadIdx.x;

  // P0: init + pack
  if (b == 0 && tid < 64) a.counts[tid] = 0;
  for (int u = b; u < 13472; u += 256) pack_unit(u, tid, a, sm);
  grid_barrier(a.bars + 0, 256);

  // P1: gemm1 (19 x 8 tiles = 152)
  if (b < 152) {
    const int bx = b % 19, by = b / 19;
    EpiArgs e;
    if (bx < 3) { e.mode = 0; e.out = a.C1; e.ldo = 384; e.coff = 0; }
    else        { e.mode = 2; e.out = a.Abuf; e.ldo = 1280; e.coff = 384; }
    gemm_tile(a.xb, 1024, a.Wcat, 1024, 1024, by * 128, bx * 128, e, sm.g.As, sm.g.Bs);
  }
  grid_barrier(a.bars + 1, 256);

  // P2: router
  router_block(b, tid, a);
  grid_barrier(a.bars + 2, 256);

  // P3: grouped GU gemm + SwiGLU (4 x 128 tiles = 512 -> 2 per block)
  for (int t = b; t < 512; t += 256) {
    const int xt = t & 3, yt = t >> 2;
    const int e_ = yt >> 1, rt = yt & 1;
    int cnt = a.counts[e_];
    if (cnt > 256) cnt = 256;
    if (rt * 128 < cnt) {
      const int base = e_ * 256 + rt * 128;
      EpiArgs ep; ep.mode = 2; ep.ldo = 256; ep.coff = 0;
      ep.out = (void*)(a.hide + (size_t)base * 256);
      gemm_tile(a.lat_g + (size_t)base * 256, 256,
                a.egut + (size_t)e_ * 131072, 256, 256, 0, xt * 128, ep,
                sm.g.As, sm.g.Bs);
    }
  }
  grid_barrier(a.bars + 3, 256);

  // P4: grouped down gemm (2 x 128 tiles = 256 -> 1 per block)
  {
    const int xt = b & 1, yt = b >> 1;
    const int e_ = yt >> 1, rt = yt & 1;
    int cnt = a.counts[e_];
    if (cnt > 256) cnt = 256;
    if (rt * 128 < cnt) {
      const int base = e_ * 256 + rt * 128;
      EpiArgs ep; ep.mode = 1; ep.ldo = 256; ep.coff = 0;
      ep.out = (void*)(a.ybuf + (size_t)base * 256);
      gemm_tile(a.hide + (size_t)base * 256, 256,
                a.edwt + (size_t)e_ * 65536, 256, 256, 0, xt * 128, ep,
                sm.g.As, sm.g.Bs);
    }
  }
  grid_barrier(a.bars + 4, 256);

  // P5: combine + z reduce
  combine_block(b, tid, a, sm);
  grid_barrier(a.bars + 5, 256);

  // P6: final gemm (8 x 8 tiles = 64)
  if (b < 64) {
    EpiArgs e; e.mode = 0; e.out = a.out; e.ldo = 1024; e.coff = 0;
    gemm_tile(a.Abuf, 1280, a.Bf, 1280, 1280, (b >> 3) * 128, (b & 7) * 128, e,
              sm.g.As, sm.g.Bs);
  }
}

// ---------------------------------------------------------------------------
extern "C" void kernel_launch(void* const* d_in, const int* in_sizes, int n_in,
                              void* d_out, int out_size, void* d_ws, size_t ws_size,
                              hipStream_t stream) {
  (void)in_sizes; (void)n_in; (void)out_size; (void)ws_size;
  MegaArgs a;
  a.x    = (const float*)d_in[0];
  a.gate = (const float*)d_in[1];
  a.bias = (const float*)d_in[2];
  a.down = (const float*)d_in[3];
  a.up   = (const float*)d_in[4];
  a.sgu  = (const float*)d_in[5];
  a.sdw  = (const float*)d_in[6];
  a.egu  = (const float*)d_in[7];
  a.edw  = (const float*)d_in[8];
  a.out  = (float*)d_out;

  char* w = (char*)d_ws;
  auto alloc = [&](size_t bytes) { char* p = w; w += (bytes + 255) & ~(size_t)255; return p; };
  a.xb    = (unsigned short*)alloc(1048576ull * 2);
  a.Wcat  = (unsigned short*)alloc(2432ull * 1024 * 2);
  a.Bf    = (unsigned short*)alloc(1024ull * 1280 * 2);
  a.egut  = (unsigned short*)alloc(64ull * 512 * 256 * 2);
  a.edwt  = (unsigned short*)alloc(64ull * 256 * 256 * 2);
  a.C1    = (float*)alloc(1024ull * 384 * 4);
  a.Abuf  = (unsigned short*)alloc(1024ull * 1280 * 2);
  a.lat_g = (unsigned short*)alloc(16384ull * 256 * 2);
  a.hide  = (unsigned short*)alloc(16384ull * 256 * 2);
  a.ybuf  = (unsigned short*)alloc(16384ull * 256 * 2);
  a.lse2  = (float*)alloc(1024 * 4);
  a.counts  = (int*)alloc(64 * 4);
  a.slot_nk = (int*)alloc(8192 * 4);
  a.gw_nk   = (float*)alloc(8192 * 4);
  a.bars    = (int*)alloc(16 * 4);

  hipMemsetAsync(a.bars, 0, 16 * 4, stream);
  moe_mega<<<dim3(256), dim3(256), 0, stream>>>(a);
}

// Round 6
// 337.880 us; speedup vs baseline: 1.1339x; 1.1339x over previous
//
#include <hip/hip_runtime.h>
#include <stdint.h>

// ---------------------------------------------------------------------------
// LatentMoE forward, MI355X (gfx950). TWO dispatches:
//  1. pack_kernel (wide, 13472 blocks): f32->bf16 convert + weight packing/
//     transposes + zero counts. Full occupancy -> HBM-bound.
//  2. moe_mega (persistent, 256 blocks x 256 thr, software grid barriers):
//     P1 gemm1(+shared SwiGLU) -> P2 router -> P3 GU gemm(+SwiGLU)
//     -> P4 down gemm -> P5 combine(+z reduce) -> P6 final gemm
// ---------------------------------------------------------------------------

using f32x4 = __attribute__((ext_vector_type(4))) float;
using s16x8 = __attribute__((ext_vector_type(8))) short;

#define MFMA_BF16(a, b, c) __builtin_amdgcn_mfma_f32_16x16x32_bf16((a), (b), (c), 0, 0, 0)

__device__ __forceinline__ unsigned short f2bf(float f) {
  union { float f; uint32_t u; } v; v.f = f;
  uint32_t u = v.u;
  u += 0x7FFFu + ((u >> 16) & 1u);
  return (unsigned short)(u >> 16);
}
__device__ __forceinline__ float bf2f(unsigned short h) {
  union { uint32_t u; float f; } v; v.u = ((uint32_t)h) << 16;
  return v.f;
}
__device__ __forceinline__ float silu_f(float x) { return x / (1.f + expf(-x)); }

__device__ __forceinline__ void cvt16(const float* __restrict__ src,
                                      unsigned short* __restrict__ dst) {
  if (src) {
#pragma unroll
    for (int i = 0; i < 4; ++i) {
      float4 v = *(const float4*)(src + i * 4);
      *(ushort4*)(dst + i * 4) =
          make_ushort4(f2bf(v.x), f2bf(v.y), f2bf(v.z), f2bf(v.w));
    }
  } else {
#pragma unroll
    for (int i = 0; i < 4; ++i) *(ushort4*)(dst + i * 4) = make_ushort4(0, 0, 0, 0);
  }
}

union SMem {
  float tp[32][33];
  struct { unsigned short As[3 * 4096]; unsigned short Bs[3 * 4096]; } g;
};

struct MegaArgs {
  const float *x, *gate, *down, *sgu, *sdw, *up, *egu, *edw, *bias;
  unsigned short *xb, *Wcat, *Bf, *egut, *edwt, *Abuf, *lat_g, *hide, *ybuf;
  float *C1, *lse2, *out;
  int *counts, *slot_nk;
  float *gw_nk;
  int *bars;  // software grid-barrier slots (zeroed before launch)
};

// ---------------------------------------------------------------------------
// Wide pack kernel: grid 13472 x 256. Units:
//  [0,608) Wcat | [608,928) Bf | [928,1184) xb | [1184,9376) egut T |
//  [9376,13472) edwt T
// ---------------------------------------------------------------------------
__global__ void pack_kernel(MegaArgs a) {
  __shared__ float tile[32][33];
  const int b = blockIdx.x, t = threadIdx.x;
  if (b == 0 && t < 64) a.counts[t] = 0;
  if (b < 608) {
    const int r = b * 4 + (t >> 6), c = (t & 63) * 16;
    const float* src;
    if (r < 64)       src = a.gate + (size_t)r * 1024 + c;
    else if (r < 320) src = a.down + (size_t)(r - 64) * 1024 + c;
    else if (r < 384) src = nullptr;
    else {
      const int i = r - 384;
      src = a.sgu + (size_t)((i >> 1) + (i & 1) * 1024) * 1024 + c;
    }
    cvt16(src, a.Wcat + (size_t)r * 1024 + c);
  } else if (b < 928) {
    const int idx = (b - 608) * 4096 + t * 16;
    const int row = idx / 1280, col = idx - row * 1280;
    const float* src = (col < 1024) ? a.sdw + (size_t)row * 1024 + col
                                    : a.up + (size_t)row * 256 + (col - 1024);
    cvt16(src, a.Bf + idx);
  } else if (b < 1184) {
    const int idx = (b - 928) * 4096 + t * 16;
    cvt16(a.x + idx, a.xb + idx);
  } else {
    const float* src; unsigned short* dst; int lds, tr, tc; bool inter;
    if (b < 9376) {
      const int q = b - 1184, e = q >> 7, tt = q & 127;
      tr = tt >> 4; tc = tt & 15; lds = 512; inter = true;
      src = a.egu + (size_t)e * 131072; dst = a.egut + (size_t)e * 131072;
    } else {
      const int q = b - 9376, e = q >> 6, tt = q & 63;
      tr = tt >> 3; tc = tt & 7; lds = 256; inter = false;
      src = a.edw + (size_t)e * 65536; dst = a.edwt + (size_t)e * 65536;
    }
    const int r = t >> 3, c4 = (t & 7) * 4;
    float4 v = *(const float4*)(src + (size_t)(tr * 32 + r) * lds + tc * 32 + c4);
    tile[r][c4 + 0] = v.x; tile[r][c4 + 1] = v.y;
    tile[r][c4 + 2] = v.z; tile[r][c4 + 3] = v.w;
    __syncthreads();
    const int n = tc * 32 + r;
    const int orow = inter ? ((n < 256) ? 2 * n : 2 * (n - 256) + 1) : n;
    ushort4 o = make_ushort4(f2bf(tile[c4 + 0][r]), f2bf(tile[c4 + 1][r]),
                             f2bf(tile[c4 + 2][r]), f2bf(tile[c4 + 3][r]));
    *(ushort4*)(dst + (size_t)orow * 256 + tr * 32 + c4) = o;
  }
}

// ---------------------------------------------------------------------------
// Software grid barrier (all 256 blocks co-resident at 1 blk/CU on 256 CUs).
// ---------------------------------------------------------------------------
__device__ __forceinline__ void grid_barrier(int* bar, int nblk) {
  __syncthreads();
  if (threadIdx.x == 0) {
    __threadfence();
    __hip_atomic_fetch_add(bar, 1, __ATOMIC_RELEASE, __HIP_MEMORY_SCOPE_AGENT);
    while (__hip_atomic_load(bar, __ATOMIC_ACQUIRE, __HIP_MEMORY_SCOPE_AGENT) < nblk)
      __builtin_amdgcn_s_sleep(2);
    __threadfence();
  }
  __syncthreads();
}

// ---------------------------------------------------------------------------
// GEMM core (R3 pipeline: triple-buffered LDS, counted vmcnt, raw s_barrier)
// ---------------------------------------------------------------------------
struct EpiArgs { int mode; void* out; int ldo; int coff; };

__device__ __forceinline__ void stage_tile(const unsigned short* __restrict__ G, int ldg,
                                           int row0, int kt, unsigned short* lbuf,
                                           int wid, int lane) {
#pragma unroll
  for (int j = 0; j < 2; ++j) {
    const int o = j * 4096 + wid * 1024 + lane * 16;
    const int kh = o >> 11;
    const int row = (o & 2047) >> 4;
    const unsigned short* src = G + (size_t)(row0 + row) * ldg + kt * 32 + kh * 8;
    __builtin_amdgcn_global_load_lds(
        (const __attribute__((address_space(1))) void*)src,
        (__attribute__((address_space(3))) void*)(lbuf + (size_t)(j * 2048 + wid * 512)),
        16, 0, 0);
  }
}

__device__ __forceinline__ void wave_fence() { asm volatile("" ::: "memory"); }

__device__ void gemm_tile(const unsigned short* __restrict__ A, int lda,
                          const unsigned short* __restrict__ B, int ldb,
                          int K, int m0, int n0, EpiArgs epi,
                          unsigned short* As, unsigned short* Bs) {
  __syncthreads();  // LDS may be in use by a previous tile/phase of this block
  const int tid = threadIdx.x;
  const int wid = tid >> 6, lane = tid & 63;
  const int wm = wid >> 1, wn = wid & 1;

  f32x4 acc[4][4] = {};
  const int NT = K >> 5;

  stage_tile(A, lda, m0, 0, As, wid, lane);
  stage_tile(B, ldb, n0, 0, Bs, wid, lane);
  if (NT > 1) {
    stage_tile(A, lda, m0, 1, As + 4096, wid, lane);
    stage_tile(B, ldb, n0, 1, Bs + 4096, wid, lane);
  }

  const int kh = lane >> 4, r16 = lane & 15;
  int cur = 0;
  for (int kt = 0; kt < NT; ++kt) {
    if (kt + 1 < NT) asm volatile("s_waitcnt vmcnt(4)" ::: "memory");
    else             asm volatile("s_waitcnt vmcnt(0)" ::: "memory");
    wave_fence();
    __builtin_amdgcn_s_barrier();
    wave_fence();

    const unsigned short* Ab = As + cur * 4096;
    const unsigned short* Bb = Bs + cur * 4096;
    s16x8 af[4], bfr[4];
#pragma unroll
    for (int m = 0; m < 4; ++m)
      af[m] = *(const s16x8*)(Ab + kh * 1024 + (wm * 64 + m * 16 + r16) * 8);
#pragma unroll
    for (int n = 0; n < 4; ++n)
      bfr[n] = *(const s16x8*)(Bb + kh * 1024 + (wn * 64 + n * 16 + r16) * 8);

    if (kt + 2 < NT) {
      const int nb = (cur + 2 >= 3) ? cur - 1 : cur + 2;
      stage_tile(A, lda, m0, kt + 2, As + nb * 4096, wid, lane);
      stage_tile(B, ldb, n0, kt + 2, Bs + nb * 4096, wid, lane);
    }

    __builtin_amdgcn_s_setprio(1);
#pragma unroll
    for (int m = 0; m < 4; ++m)
#pragma unroll
      for (int n = 0; n < 4; ++n)
        acc[m][n] = MFMA_BF16(af[m], bfr[n], acc[m][n]);
    __builtin_amdgcn_s_setprio(0);

    cur = (cur + 1 == 3) ? 0 : cur + 1;
  }

#pragma unroll
  for (int m = 0; m < 4; ++m) {
    const int rb = m0 + wm * 64 + m * 16 + (lane >> 4) * 4;
#pragma unroll
    for (int n = 0; n < 4; ++n) {
      const int c = n0 + wn * 64 + n * 16 + (lane & 15);
      if (epi.mode == 0) {
        float* O = (float*)epi.out;
#pragma unroll
        for (int j = 0; j < 4; ++j) O[(size_t)(rb + j) * epi.ldo + c] = acc[m][n][j];
      } else if (epi.mode == 1) {
        unsigned short* O = (unsigned short*)epi.out;
#pragma unroll
        for (int j = 0; j < 4; ++j)
          O[(size_t)(rb + j) * epi.ldo + c] = f2bf(acc[m][n][j]);
      } else {
        unsigned short* O = (unsigned short*)epi.out;
        const int col = (c - epi.coff) >> 1;
#pragma unroll
        for (int j = 0; j < 4; ++j) {
          const float v = acc[m][n][j];
          const float u = __shfl_xor(v, 1);
          if (!(lane & 1))
            O[(size_t)(rb + j) * epi.ldo + col] = f2bf(silu_f(v) * u);
        }
      }
    }
  }
}

// ---------------------------------------------------------------------------
// P2: router (one wave per token; 4 tokens per block)
// ---------------------------------------------------------------------------
__device__ void router_block(int b, int tid, const MegaArgs& a) {
  const int n = b * 4 + (tid >> 6);
  const int lane = tid & 63;
  const float* row = a.C1 + (size_t)n * 384;
  const float logit = row[lane];

  float mx = logit;
#pragma unroll
  for (int d = 32; d; d >>= 1) mx = fmaxf(mx, __shfl_xor(mx, d));
  float se = expf(logit - mx);
#pragma unroll
  for (int d = 32; d; d >>= 1) se += __shfl_xor(se, d);
  if (lane == 0) {
    const float lse = mx + logf(se);
    a.lse2[n] = lse * lse;
  }

  const float aff = 1.f / (1.f + expf(-logit));
  float s = aff + a.bias[lane];

  float asum = 0.f;
  int e_mine = 0; float a_mine = 0.f;
#pragma unroll
  for (int k = 0; k < 8; ++k) {
    float m2 = s;
#pragma unroll
    for (int d = 32; d; d >>= 1) m2 = fmaxf(m2, __shfl_xor(m2, d));
    const unsigned long long blt = __ballot(s == m2);
    const int idx = __ffsll(blt) - 1;
    const float af_ = __shfl(aff, idx);
    asum += af_;
    if (lane == k) { e_mine = idx; a_mine = af_; }
    if (lane == idx) s = -3.0e38f;
  }
  const float inv = 1.f / (asum + 1e-9f);

  int slot = 0;
  if (lane < 8) {
    int pos = atomicAdd(&a.counts[e_mine], 1);
    if (pos > 255) pos = 255;
    slot = e_mine * 256 + pos;
    a.slot_nk[(size_t)n * 8 + lane] = slot;
    a.gw_nk[(size_t)n * 8 + lane] = a_mine * inv;
  }

  const float4 lv = *(const float4*)(row + 64 + lane * 4);
  const ushort4 lb = make_ushort4(f2bf(lv.x), f2bf(lv.y), f2bf(lv.z), f2bf(lv.w));
#pragma unroll
  for (int k = 0; k < 8; ++k) {
    const int sl = __shfl(slot, k);
    *(ushort4*)(a.lat_g + (size_t)sl * 256 + lane * 4) = lb;
  }
}

// ---------------------------------------------------------------------------
// P5: combine (4 tokens per block) + z-loss reduce on block 0
// ---------------------------------------------------------------------------
__device__ void combine_block(int b, int tid, const MegaArgs& a, SMem& sm) {
  const int n = b * 4 + (tid >> 6);
  const int l4 = (tid & 63) * 4;
  float a0 = 0.f, a1 = 0.f, a2 = 0.f, a3 = 0.f;
#pragma unroll
  for (int k = 0; k < 8; ++k) {
    const int sl = a.slot_nk[(size_t)n * 8 + k];
    const float g = a.gw_nk[(size_t)n * 8 + k];
    const ushort4 yv = *(const ushort4*)(a.ybuf + (size_t)sl * 256 + l4);
    a0 += g * bf2f(yv.x); a1 += g * bf2f(yv.y);
    a2 += g * bf2f(yv.z); a3 += g * bf2f(yv.w);
  }
  *(ushort4*)(a.Abuf + (size_t)n * 1280 + 1024 + l4) =
      make_ushort4(f2bf(a0), f2bf(a1), f2bf(a2), f2bf(a3));

  if (b == 0) {
    __syncthreads();
    float s = a.lse2[tid] + a.lse2[tid + 256] + a.lse2[tid + 512] + a.lse2[tid + 768];
    ((float*)sm.tp)[tid] = s;
    __syncthreads();
    for (int d = 128; d; d >>= 1) {
      if (tid < d) ((float*)sm.tp)[tid] += ((float*)sm.tp)[tid + d];
      __syncthreads();
    }
    if (tid == 0) a.out[1048576] = 0.001f * ((float*)sm.tp)[0] * (1.f / 1024.f);
  }
}

// ---------------------------------------------------------------------------
__global__ __launch_bounds__(256, 1) void moe_mega(MegaArgs a) {
  __shared__ SMem sm;
  const int b = blockIdx.x, tid = threadIdx.x;

  // P1: gemm1 (19 x 8 tiles = 152)
  if (b < 152) {
    const int bx = b % 19, by = b / 19;
    EpiArgs e;
    if (bx < 3) { e.mode = 0; e.out = a.C1; e.ldo = 384; e.coff = 0; }
    else        { e.mode = 2; e.out = a.Abuf; e.ldo = 1280; e.coff = 384; }
    gemm_tile(a.xb, 1024, a.Wcat, 1024, 1024, by * 128, bx * 128, e, sm.g.As, sm.g.Bs);
  }
  grid_barrier(a.bars + 0, 256);

  // P2: router
  router_block(b, tid, a);
  grid_barrier(a.bars + 1, 256);

  // P3: grouped GU gemm + SwiGLU (4 x 128 tiles = 512 -> 2 per block)
  for (int t = b; t < 512; t += 256) {
    const int xt = t & 3, yt = t >> 2;
    const int e_ = yt >> 1, rt = yt & 1;
    int cnt = a.counts[e_];
    if (cnt > 256) cnt = 256;
    if (rt * 128 < cnt) {
      const int base = e_ * 256 + rt * 128;
      EpiArgs ep; ep.mode = 2; ep.ldo = 256; ep.coff = 0;
      ep.out = (void*)(a.hide + (size_t)base * 256);
      gemm_tile(a.lat_g + (size_t)base * 256, 256,
                a.egut + (size_t)e_ * 131072, 256, 256, 0, xt * 128, ep,
                sm.g.As, sm.g.Bs);
    }
  }
  grid_barrier(a.bars + 2, 256);

  // P4: grouped down gemm (2 x 128 tiles = 256 -> 1 per block)
  {
    const int xt = b & 1, yt = b >> 1;
    const int e_ = yt >> 1, rt = yt & 1;
    int cnt = a.counts[e_];
    if (cnt > 256) cnt = 256;
    if (rt * 128 < cnt) {
      const int base = e_ * 256 + rt * 128;
      EpiArgs ep; ep.mode = 1; ep.ldo = 256; ep.coff = 0;
      ep.out = (void*)(a.ybuf + (size_t)base * 256);
      gemm_tile(a.hide + (size_t)base * 256, 256,
                a.edwt + (size_t)e_ * 65536, 256, 256, 0, xt * 128, ep,
                sm.g.As, sm.g.Bs);
    }
  }
  grid_barrier(a.bars + 3, 256);

  // P5: combine + z reduce
  combine_block(b, tid, a, sm);
  grid_barrier(a.bars + 4, 256);

  // P6: final gemm (8 x 8 tiles = 64)
  if (b < 64) {
    EpiArgs e; e.mode = 0; e.out = a.out; e.ldo = 1024; e.coff = 0;
    gemm_tile(a.Abuf, 1280, a.Bf, 1280, 1280, (b >> 3) * 128, (b & 7) * 128, e,
              sm.g.As, sm.g.Bs);
  }
}

// ---------------------------------------------------------------------------
extern "C" void kernel_launch(void* const* d_in, const int* in_sizes, int n_in,
                              void* d_out, int out_size, void* d_ws, size_t ws_size,
                              hipStream_t stream) {
  (void)in_sizes; (void)n_in; (void)out_size; (void)ws_size;
  MegaArgs a;
  a.x    = (const float*)d_in[0];
  a.gate = (const float*)d_in[1];
  a.bias = (const float*)d_in[2];
  a.down = (const float*)d_in[3];
  a.up   = (const float*)d_in[4];
  a.sgu  = (const float*)d_in[5];
  a.sdw  = (const float*)d_in[6];
  a.egu  = (const float*)d_in[7];
  a.edw  = (const float*)d_in[8];
  a.out  = (float*)d_out;

  char* w = (char*)d_ws;
  auto alloc = [&](size_t bytes) { char* p = w; w += (bytes + 255) & ~(size_t)255; return p; };
  a.xb    = (unsigned short*)alloc(1048576ull * 2);
  a.Wcat  = (unsigned short*)alloc(2432ull * 1024 * 2);
  a.Bf    = (unsigned short*)alloc(1024ull * 1280 * 2);
  a.egut  = (unsigned short*)alloc(64ull * 512 * 256 * 2);
  a.edwt  = (unsigned short*)alloc(64ull * 256 * 256 * 2);
  a.C1    = (float*)alloc(1024ull * 384 * 4);
  a.Abuf  = (unsigned short*)alloc(1024ull * 1280 * 2);
  a.lat_g = (unsigned short*)alloc(16384ull * 256 * 2);
  a.hide  = (unsigned short*)alloc(16384ull * 256 * 2);
  a.ybuf  = (unsigned short*)alloc(16384ull * 256 * 2);
  a.lse2  = (float*)alloc(1024 * 4);
  a.counts  = (int*)alloc(64 * 4);
  a.slot_nk = (int*)alloc(8192 * 4);
  a.gw_nk   = (float*)alloc(8192 * 4);
  a.bars    = (int*)alloc(16 * 4);

  hipMemsetAsync(a.bars, 0, 16 * 4, stream);
  pack_kernel<<<dim3(13472), dim3(256), 0, stream>>>(a);
  moe_mega<<<dim3(256), dim3(256), 0, stream>>>(a);
}

// Round 7
// 214.690 us; speedup vs baseline: 1.7845x; 1.5738x over previous
//
#include <hip/hip_runtime.h>
#include <stdint.h>

// ---------------------------------------------------------------------------
// LatentMoE forward, MI355X (gfx950). TWO dispatches:
//  1. pack_kernel (wide, 13472 blocks): f32->bf16 convert + weight packing/
//     transposes + zero counts. Full occupancy -> HBM-bound.
//  2. moe_mega (persistent, 256 blocks x 256 thr, software grid barriers):
//     P1 gemm1(+shared SwiGLU) -> P2 router -> P3 GU gemm(+SwiGLU)
//     -> P4 down gemm -> P5 combine(+z reduce) -> P6 final gemm
// R7: grid_barrier spin uses RELAXED atomic loads (no per-poll buffer_inv /
// L2 invalidate) + ONE acquire fence on exit. R6's acquire-per-poll was
// invalidating L2 device-wide continuously -> 234 GB/s effective staging.
// ---------------------------------------------------------------------------

using f32x4 = __attribute__((ext_vector_type(4))) float;
using s16x8 = __attribute__((ext_vector_type(8))) short;

#define MFMA_BF16(a, b, c) __builtin_amdgcn_mfma_f32_16x16x32_bf16((a), (b), (c), 0, 0, 0)

__device__ __forceinline__ unsigned short f2bf(float f) {
  union { float f; uint32_t u; } v; v.f = f;
  uint32_t u = v.u;
  u += 0x7FFFu + ((u >> 16) & 1u);
  return (unsigned short)(u >> 16);
}
__device__ __forceinline__ float bf2f(unsigned short h) {
  union { uint32_t u; float f; } v; v.u = ((uint32_t)h) << 16;
  return v.f;
}
__device__ __forceinline__ float silu_f(float x) { return x / (1.f + expf(-x)); }

__device__ __forceinline__ void cvt16(const float* __restrict__ src,
                                      unsigned short* __restrict__ dst) {
  if (src) {
#pragma unroll
    for (int i = 0; i < 4; ++i) {
      float4 v = *(const float4*)(src + i * 4);
      *(ushort4*)(dst + i * 4) =
          make_ushort4(f2bf(v.x), f2bf(v.y), f2bf(v.z), f2bf(v.w));
    }
  } else {
#pragma unroll
    for (int i = 0; i < 4; ++i) *(ushort4*)(dst + i * 4) = make_ushort4(0, 0, 0, 0);
  }
}

union SMem {
  float tp[32][33];
  struct { unsigned short As[3 * 4096]; unsigned short Bs[3 * 4096]; } g;
};

struct MegaArgs {
  const float *x, *gate, *down, *sgu, *sdw, *up, *egu, *edw, *bias;
  unsigned short *xb, *Wcat, *Bf, *egut, *edwt, *Abuf, *lat_g, *hide, *ybuf;
  float *C1, *lse2, *out;
  int *counts, *slot_nk;
  float *gw_nk;
  int *bars;  // software grid-barrier slots (zeroed before launch)
};

// ---------------------------------------------------------------------------
// Wide pack kernel: grid 13472 x 256. Units:
//  [0,608) Wcat | [608,928) Bf | [928,1184) xb | [1184,9376) egut T |
//  [9376,13472) edwt T
// ---------------------------------------------------------------------------
__global__ void pack_kernel(MegaArgs a) {
  __shared__ float tile[32][33];
  const int b = blockIdx.x, t = threadIdx.x;
  if (b == 0 && t < 64) a.counts[t] = 0;
  if (b < 608) {
    const int r = b * 4 + (t >> 6), c = (t & 63) * 16;
    const float* src;
    if (r < 64)       src = a.gate + (size_t)r * 1024 + c;
    else if (r < 320) src = a.down + (size_t)(r - 64) * 1024 + c;
    else if (r < 384) src = nullptr;
    else {
      const int i = r - 384;
      src = a.sgu + (size_t)((i >> 1) + (i & 1) * 1024) * 1024 + c;
    }
    cvt16(src, a.Wcat + (size_t)r * 1024 + c);
  } else if (b < 928) {
    const int idx = (b - 608) * 4096 + t * 16;
    const int row = idx / 1280, col = idx - row * 1280;
    const float* src = (col < 1024) ? a.sdw + (size_t)row * 1024 + col
                                    : a.up + (size_t)row * 256 + (col - 1024);
    cvt16(src, a.Bf + idx);
  } else if (b < 1184) {
    const int idx = (b - 928) * 4096 + t * 16;
    cvt16(a.x + idx, a.xb + idx);
  } else {
    const float* src; unsigned short* dst; int lds, tr, tc; bool inter;
    if (b < 9376) {
      const int q = b - 1184, e = q >> 7, tt = q & 127;
      tr = tt >> 4; tc = tt & 15; lds = 512; inter = true;
      src = a.egu + (size_t)e * 131072; dst = a.egut + (size_t)e * 131072;
    } else {
      const int q = b - 9376, e = q >> 6, tt = q & 63;
      tr = tt >> 3; tc = tt & 7; lds = 256; inter = false;
      src = a.edw + (size_t)e * 65536; dst = a.edwt + (size_t)e * 65536;
    }
    const int r = t >> 3, c4 = (t & 7) * 4;
    float4 v = *(const float4*)(src + (size_t)(tr * 32 + r) * lds + tc * 32 + c4);
    tile[r][c4 + 0] = v.x; tile[r][c4 + 1] = v.y;
    tile[r][c4 + 2] = v.z; tile[r][c4 + 3] = v.w;
    __syncthreads();
    const int n = tc * 32 + r;
    const int orow = inter ? ((n < 256) ? 2 * n : 2 * (n - 256) + 1) : n;
    ushort4 o = make_ushort4(f2bf(tile[c4 + 0][r]), f2bf(tile[c4 + 1][r]),
                             f2bf(tile[c4 + 2][r]), f2bf(tile[c4 + 3][r]));
    *(ushort4*)(dst + (size_t)orow * 256 + tr * 32 + c4) = o;
  }
}

// ---------------------------------------------------------------------------
// Software grid barrier (all 256 blocks co-resident at 1 blk/CU on 256 CUs).
// RELAXED polls (no L2 invalidate per poll); single acquire fence on exit.
// ---------------------------------------------------------------------------
__device__ __forceinline__ void grid_barrier(int* bar, int nblk) {
  __syncthreads();
  if (threadIdx.x == 0) {
    __hip_atomic_fetch_add(bar, 1, __ATOMIC_RELEASE, __HIP_MEMORY_SCOPE_AGENT);
    while (__hip_atomic_load(bar, __ATOMIC_RELAXED, __HIP_MEMORY_SCOPE_AGENT) < nblk)
      __builtin_amdgcn_s_sleep(8);
    __builtin_amdgcn_fence(__ATOMIC_ACQUIRE, "agent");
  }
  __syncthreads();
}

// ---------------------------------------------------------------------------
// GEMM core (R3 pipeline: triple-buffered LDS, counted vmcnt, raw s_barrier)
// ---------------------------------------------------------------------------
struct EpiArgs { int mode; void* out; int ldo; int coff; };

__device__ __forceinline__ void stage_tile(const unsigned short* __restrict__ G, int ldg,
                                           int row0, int kt, unsigned short* lbuf,
                                           int wid, int lane) {
#pragma unroll
  for (int j = 0; j < 2; ++j) {
    const int o = j * 4096 + wid * 1024 + lane * 16;
    const int kh = o >> 11;
    const int row = (o & 2047) >> 4;
    const unsigned short* src = G + (size_t)(row0 + row) * ldg + kt * 32 + kh * 8;
    __builtin_amdgcn_global_load_lds(
        (const __attribute__((address_space(1))) void*)src,
        (__attribute__((address_space(3))) void*)(lbuf + (size_t)(j * 2048 + wid * 512)),
        16, 0, 0);
  }
}

__device__ __forceinline__ void wave_fence() { asm volatile("" ::: "memory"); }

__device__ void gemm_tile(const unsigned short* __restrict__ A, int lda,
                          const unsigned short* __restrict__ B, int ldb,
                          int K, int m0, int n0, EpiArgs epi,
                          unsigned short* As, unsigned short* Bs) {
  __syncthreads();  // LDS may be in use by a previous tile/phase of this block
  const int tid = threadIdx.x;
  const int wid = tid >> 6, lane = tid & 63;
  const int wm = wid >> 1, wn = wid & 1;

  f32x4 acc[4][4] = {};
  const int NT = K >> 5;

  stage_tile(A, lda, m0, 0, As, wid, lane);
  stage_tile(B, ldb, n0, 0, Bs, wid, lane);
  if (NT > 1) {
    stage_tile(A, lda, m0, 1, As + 4096, wid, lane);
    stage_tile(B, ldb, n0, 1, Bs + 4096, wid, lane);
  }

  const int kh = lane >> 4, r16 = lane & 15;
  int cur = 0;
  for (int kt = 0; kt < NT; ++kt) {
    if (kt + 1 < NT) asm volatile("s_waitcnt vmcnt(4)" ::: "memory");
    else             asm volatile("s_waitcnt vmcnt(0)" ::: "memory");
    wave_fence();
    __builtin_amdgcn_s_barrier();
    wave_fence();

    const unsigned short* Ab = As + cur * 4096;
    const unsigned short* Bb = Bs + cur * 4096;
    s16x8 af[4], bfr[4];
#pragma unroll
    for (int m = 0; m < 4; ++m)
      af[m] = *(const s16x8*)(Ab + kh * 1024 + (wm * 64 + m * 16 + r16) * 8);
#pragma unroll
    for (int n = 0; n < 4; ++n)
      bfr[n] = *(const s16x8*)(Bb + kh * 1024 + (wn * 64 + n * 16 + r16) * 8);

    if (kt + 2 < NT) {
      const int nb = (cur + 2 >= 3) ? cur - 1 : cur + 2;
      stage_tile(A, lda, m0, kt + 2, As + nb * 4096, wid, lane);
      stage_tile(B, ldb, n0, kt + 2, Bs + nb * 4096, wid, lane);
    }

    __builtin_amdgcn_s_setprio(1);
#pragma unroll
    for (int m = 0; m < 4; ++m)
#pragma unroll
      for (int n = 0; n < 4; ++n)
        acc[m][n] = MFMA_BF16(af[m], bfr[n], acc[m][n]);
    __builtin_amdgcn_s_setprio(0);

    cur = (cur + 1 == 3) ? 0 : cur + 1;
  }

#pragma unroll
  for (int m = 0; m < 4; ++m) {
    const int rb = m0 + wm * 64 + m * 16 + (lane >> 4) * 4;
#pragma unroll
    for (int n = 0; n < 4; ++n) {
      const int c = n0 + wn * 64 + n * 16 + (lane & 15);
      if (epi.mode == 0) {
        float* O = (float*)epi.out;
#pragma unroll
        for (int j = 0; j < 4; ++j) O[(size_t)(rb + j) * epi.ldo + c] = acc[m][n][j];
      } else if (epi.mode == 1) {
        unsigned short* O = (unsigned short*)epi.out;
#pragma unroll
        for (int j = 0; j < 4; ++j)
          O[(size_t)(rb + j) * epi.ldo + c] = f2bf(acc[m][n][j]);
      } else {
        unsigned short* O = (unsigned short*)epi.out;
        const int col = (c - epi.coff) >> 1;
#pragma unroll
        for (int j = 0; j < 4; ++j) {
          const float v = acc[m][n][j];
          const float u = __shfl_xor(v, 1);
          if (!(lane & 1))
            O[(size_t)(rb + j) * epi.ldo + col] = f2bf(silu_f(v) * u);
        }
      }
    }
  }
}

// ---------------------------------------------------------------------------
// P2: router (one wave per token; 4 tokens per block)
// ---------------------------------------------------------------------------
__device__ void router_block(int b, int tid, const MegaArgs& a) {
  const int n = b * 4 + (tid >> 6);
  const int lane = tid & 63;
  const float* row = a.C1 + (size_t)n * 384;
  const float logit = row[lane];

  float mx = logit;
#pragma unroll
  for (int d = 32; d; d >>= 1) mx = fmaxf(mx, __shfl_xor(mx, d));
  float se = expf(logit - mx);
#pragma unroll
  for (int d = 32; d; d >>= 1) se += __shfl_xor(se, d);
  if (lane == 0) {
    const float lse = mx + logf(se);
    a.lse2[n] = lse * lse;
  }

  const float aff = 1.f / (1.f + expf(-logit));
  float s = aff + a.bias[lane];

  float asum = 0.f;
  int e_mine = 0; float a_mine = 0.f;
#pragma unroll
  for (int k = 0; k < 8; ++k) {
    float m2 = s;
#pragma unroll
    for (int d = 32; d; d >>= 1) m2 = fmaxf(m2, __shfl_xor(m2, d));
    const unsigned long long blt = __ballot(s == m2);
    const int idx = __ffsll(blt) - 1;
    const float af_ = __shfl(aff, idx);
    asum += af_;
    if (lane == k) { e_mine = idx; a_mine = af_; }
    if (lane == idx) s = -3.0e38f;
  }
  const float inv = 1.f / (asum + 1e-9f);

  int slot = 0;
  if (lane < 8) {
    int pos = atomicAdd(&a.counts[e_mine], 1);
    if (pos > 255) pos = 255;
    slot = e_mine * 256 + pos;
    a.slot_nk[(size_t)n * 8 + lane] = slot;
    a.gw_nk[(size_t)n * 8 + lane] = a_mine * inv;
  }

  const float4 lv = *(const float4*)(row + 64 + lane * 4);
  const ushort4 lb = make_ushort4(f2bf(lv.x), f2bf(lv.y), f2bf(lv.z), f2bf(lv.w));
#pragma unroll
  for (int k = 0; k < 8; ++k) {
    const int sl = __shfl(slot, k);
    *(ushort4*)(a.lat_g + (size_t)sl * 256 + lane * 4) = lb;
  }
}

// ---------------------------------------------------------------------------
// P5: combine (4 tokens per block) + z-loss reduce on block 0
// ---------------------------------------------------------------------------
__device__ void combine_block(int b, int tid, const MegaArgs& a, SMem& sm) {
  const int n = b * 4 + (tid >> 6);
  const int l4 = (tid & 63) * 4;
  float a0 = 0.f, a1 = 0.f, a2 = 0.f, a3 = 0.f;
#pragma unroll
  for (int k = 0; k < 8; ++k) {
    const int sl = a.slot_nk[(size_t)n * 8 + k];
    const float g = a.gw_nk[(size_t)n * 8 + k];
    const ushort4 yv = *(const ushort4*)(a.ybuf + (size_t)sl * 256 + l4);
    a0 += g * bf2f(yv.x); a1 += g * bf2f(yv.y);
    a2 += g * bf2f(yv.z); a3 += g * bf2f(yv.w);
  }
  *(ushort4*)(a.Abuf + (size_t)n * 1280 + 1024 + l4) =
      make_ushort4(f2bf(a0), f2bf(a1), f2bf(a2), f2bf(a3));

  if (b == 0) {
    __syncthreads();
    float s = a.lse2[tid] + a.lse2[tid + 256] + a.lse2[tid + 512] + a.lse2[tid + 768];
    ((float*)sm.tp)[tid] = s;
    __syncthreads();
    for (int d = 128; d; d >>= 1) {
      if (tid < d) ((float*)sm.tp)[tid] += ((float*)sm.tp)[tid + d];
      __syncthreads();
    }
    if (tid == 0) a.out[1048576] = 0.001f * ((float*)sm.tp)[0] * (1.f / 1024.f);
  }
}

// ---------------------------------------------------------------------------
__global__ __launch_bounds__(256, 1) void moe_mega(MegaArgs a) {
  __shared__ SMem sm;
  const int b = blockIdx.x, tid = threadIdx.x;

  // P1: gemm1 (19 x 8 tiles = 152)
  if (b < 152) {
    const int bx = b % 19, by = b / 19;
    EpiArgs e;
    if (bx < 3) { e.mode = 0; e.out = a.C1; e.ldo = 384; e.coff = 0; }
    else        { e.mode = 2; e.out = a.Abuf; e.ldo = 1280; e.coff = 384; }
    gemm_tile(a.xb, 1024, a.Wcat, 1024, 1024, by * 128, bx * 128, e, sm.g.As, sm.g.Bs);
  }
  grid_barrier(a.bars + 0, 256);

  // P2: router
  router_block(b, tid, a);
  grid_barrier(a.bars + 1, 256);

  // P3: grouped GU gemm + SwiGLU (4 x 128 tiles = 512 -> 2 per block)
  for (int t = b; t < 512; t += 256) {
    const int xt = t & 3, yt = t >> 2;
    const int e_ = yt >> 1, rt = yt & 1;
    int cnt = a.counts[e_];
    if (cnt > 256) cnt = 256;
    if (rt * 128 < cnt) {
      const int base = e_ * 256 + rt * 128;
      EpiArgs ep; ep.mode = 2; ep.ldo = 256; ep.coff = 0;
      ep.out = (void*)(a.hide + (size_t)base * 256);
      gemm_tile(a.lat_g + (size_t)base * 256, 256,
                a.egut + (size_t)e_ * 131072, 256, 256, 0, xt * 128, ep,
                sm.g.As, sm.g.Bs);
    }
  }
  grid_barrier(a.bars + 2, 256);

  // P4: grouped down gemm (2 x 128 tiles = 256 -> 1 per block)
  {
    const int xt = b & 1, yt = b >> 1;
    const int e_ = yt >> 1, rt = yt & 1;
    int cnt = a.counts[e_];
    if (cnt > 256) cnt = 256;
    if (rt * 128 < cnt) {
      const int base = e_ * 256 + rt * 128;
      EpiArgs ep; ep.mode = 1; ep.ldo = 256; ep.coff = 0;
      ep.out = (void*)(a.ybuf + (size_t)base * 256);
      gemm_tile(a.hide + (size_t)base * 256, 256,
                a.edwt + (size_t)e_ * 65536, 256, 256, 0, xt * 128, ep,
                sm.g.As, sm.g.Bs);
    }
  }
  grid_barrier(a.bars + 3, 256);

  // P5: combine + z reduce
  combine_block(b, tid, a, sm);
  grid_barrier(a.bars + 4, 256);

  // P6: final gemm (8 x 8 tiles = 64)
  if (b < 64) {
    EpiArgs e; e.mode = 0; e.out = a.out; e.ldo = 1024; e.coff = 0;
    gemm_tile(a.Abuf, 1280, a.Bf, 1280, 1280, (b >> 3) * 128, (b & 7) * 128, e,
              sm.g.As, sm.g.Bs);
  }
}

// ---------------------------------------------------------------------------
extern "C" void kernel_launch(void* const* d_in, const int* in_sizes, int n_in,
                              void* d_out, int out_size, void* d_ws, size_t ws_size,
                              hipStream_t stream) {
  (void)in_sizes; (void)n_in; (void)out_size; (void)ws_size;
  MegaArgs a;
  a.x    = (const float*)d_in[0];
  a.gate = (const float*)d_in[1];
  a.bias = (const float*)d_in[2];
  a.down = (const float*)d_in[3];
  a.up   = (const float*)d_in[4];
  a.sgu  = (const float*)d_in[5];
  a.sdw  = (const float*)d_in[6];
  a.egu  = (const float*)d_in[7];
  a.edw  = (const float*)d_in[8];
  a.out  = (float*)d_out;

  char* w = (char*)d_ws;
  auto alloc = [&](size_t bytes) { char* p = w; w += (bytes + 255) & ~(size_t)255; return p; };
  a.xb    = (unsigned short*)alloc(1048576ull * 2);
  a.Wcat  = (unsigned short*)alloc(2432ull * 1024 * 2);
  a.Bf    = (unsigned short*)alloc(1024ull * 1280 * 2);
  a.egut  = (unsigned short*)alloc(64ull * 512 * 256 * 2);
  a.edwt  = (unsigned short*)alloc(64ull * 256 * 256 * 2);
  a.C1    = (float*)alloc(1024ull * 384 * 4);
  a.Abuf  = (unsigned short*)alloc(1024ull * 1280 * 2);
  a.lat_g = (unsigned short*)alloc(16384ull * 256 * 2);
  a.hide  = (unsigned short*)alloc(16384ull * 256 * 2);
  a.ybuf  = (unsigned short*)alloc(16384ull * 256 * 2);
  a.lse2  = (float*)alloc(1024 * 4);
  a.counts  = (int*)alloc(64 * 4);
  a.slot_nk = (int*)alloc(8192 * 4);
  a.gw_nk   = (float*)alloc(8192 * 4);
  a.bars    = (int*)alloc(16 * 4);

  hipMemsetAsync(a.bars, 0, 16 * 4, stream);
  pack_kernel<<<dim3(13472), dim3(256), 0, stream>>>(a);
  moe_mega<<<dim3(256), dim3(256), 0, stream>>>(a);
}